// Round 1
// baseline (319.949 us; speedup 1.0000x reference)
//
#include <hip/hip_runtime.h>
#include <math.h>

#define MAX_SEQ   1024
#define NUM_HEADS 16
#define NUM_KV    4
#define HEAD_DIM  128
#define HIDDEN    2048
#define GROUPS    4
#define EPS       1e-6f
#define THETA     1000000.0f
#define SCALE     0.08838834764831845f  /* 1/sqrt(128) */
#define NSPLIT    8
#define CHUNK     128

// workspace layout (float offsets)
#define QBUF 0                    // 32*16*128 = 65536
#define KBUF 65536                // 32*4*128  = 16384
#define VBUF 81920                // 16384
#define PART 98304                // 1024 blocks * 4 heads * 130 = 532480
#define AOUT 630784               // 32*2048 = 65536
// total 696320 floats = 2.79 MB

// ---------------- Kernel 1: QKV projection + RMSNorm + RoPE ----------------
__global__ __launch_bounds__(256) void qkv_kernel(
    const float* __restrict__ x, const float* __restrict__ position,
    const float* __restrict__ wq, const float* __restrict__ wk,
    const float* __restrict__ wv, const float* __restrict__ qnw,
    const float* __restrict__ knw, float* __restrict__ ws)
{
    __shared__ float xs[HIDDEN];
    __shared__ float rv[HEAD_DIM];
    __shared__ float snorm;
    const int blk = blockIdx.x;
    const int b = blk / 24, hid = blk % 24;
    const int tid = threadIdx.x, lane = tid & 63, wave = tid >> 6;

    // stage x[b][0:2048] into LDS (float4, coalesced)
    const float4* xg = (const float4*)(x + (size_t)b * HIDDEN);
    for (int i = 0; i < HIDDEN / 4; i += 256)
        ((float4*)xs)[i + tid] = xg[i + tid];
    __syncthreads();

    const float* W;
    int type, hh;                       // 0=q, 1=k, 2=v
    if (hid < 16)      { type = 0; hh = hid;      W = wq + (size_t)hh * HEAD_DIM * HIDDEN; }
    else if (hid < 20) { type = 1; hh = hid - 16; W = wk + (size_t)hh * HEAD_DIM * HIDDEN; }
    else               { type = 2; hh = hid - 20; W = wv + (size_t)hh * HEAD_DIM * HIDDEN; }

    // wave-per-row GEMV: 128 rows, 4 waves -> 32 rows/wave
    for (int r = wave; r < HEAD_DIM; r += 4) {
        const float4* wr = (const float4*)(W + (size_t)r * HIDDEN);
        float sum = 0.f;
        #pragma unroll
        for (int j = 0; j < 8; ++j) {          // 512 float4 / 64 lanes
            float4 w4 = wr[lane + 64 * j];
            float4 x4 = ((const float4*)xs)[lane + 64 * j];
            sum += w4.x * x4.x + w4.y * x4.y + w4.z * x4.z + w4.w * x4.w;
        }
        #pragma unroll
        for (int off = 32; off; off >>= 1) sum += __shfl_xor(sum, off);
        if (lane == 0) rv[r] = sum;
    }
    __syncthreads();

    float* outp;
    if (type == 0)      outp = ws + QBUF + ((size_t)b * NUM_HEADS + hh) * HEAD_DIM;
    else if (type == 1) outp = ws + KBUF + ((size_t)b * NUM_KV + hh) * HEAD_DIM;
    else                outp = ws + VBUF + ((size_t)b * NUM_KV + hh) * HEAD_DIM;

    if (type == 2) {                    // v: no norm, no rope
        if (tid < HEAD_DIM) outp[tid] = rv[tid];
        return;
    }

    // RMSNorm over the 128-dim head
    if (wave == 0) {
        float t2 = rv[lane] * rv[lane] + rv[lane + 64] * rv[lane + 64];
        #pragma unroll
        for (int off = 32; off; off >>= 1) t2 += __shfl_xor(t2, off);
        if (lane == 0) snorm = rsqrtf(t2 * (1.0f / HEAD_DIM) + EPS);
    }
    __syncthreads();

    const float* nw = (type == 0) ? qnw : knw;
    if (tid < 64) {
        const float p = position[0];
        const float norm = snorm;
        float n1 = rv[tid]      * norm * nw[tid];
        float n2 = rv[tid + 64] * norm * nw[tid + 64];
        float invf = __powf(THETA, -(float)tid * (1.0f / 64.0f));
        float f = p * invf;
        float s, c;
        __sincosf(f, &s, &c);
        outp[tid]      = n1 * c - n2 * s;
        outp[tid + 64] = n2 * c + n1 * s;
    }
}

// ---------------- Kernel 2: flash-decode attention (split over seq) --------
__global__ __launch_bounds__(256) void attn_kernel(
    const float* __restrict__ kcache, const float* __restrict__ vcache,
    const float* __restrict__ position, float* __restrict__ ws)
{
    const int blk = blockIdx.x;         // (b*4+kv)*NSPLIT + split
    const int split = blk & (NSPLIT - 1);
    const int bk = blk >> 3;            // b*4+kv
    const int tid = threadIdx.x, lane = tid & 63, wave = tid >> 6;
    const int b = bk >> 2, kv = bk & 3;
    const int pos = (int)position[0];

    // q fragments: lane holds dims (2*lane, 2*lane+1) for each of 4 group heads
    const float* qb = ws + QBUF + ((size_t)b * NUM_HEADS + kv * GROUPS) * HEAD_DIM;
    float2 q2[4];
    #pragma unroll
    for (int g = 0; g < 4; ++g)
        q2[g] = ((const float2*)(qb + g * HEAD_DIM))[lane];

    const float* kc = kcache + (size_t)bk * MAX_SEQ * HEAD_DIM;
    const float* vc = vcache + (size_t)bk * MAX_SEQ * HEAD_DIM;
    const float* knew = ws + KBUF + (size_t)bk * HEAD_DIM;
    const float* vnew = ws + VBUF + (size_t)bk * HEAD_DIM;

    float m[4], l[4]; float2 acc[4];
    #pragma unroll
    for (int g = 0; g < 4; ++g) { m[g] = -1e30f; l[g] = 0.f; acc[g] = make_float2(0.f, 0.f); }

    const int t0 = split * CHUNK;
    const int tend = min(t0 + CHUNK, pos + 1);
    for (int t = t0 + wave; t < tend; t += 4) {
        const float2* kp = (const float2*)((t == pos) ? knew : (kc + (size_t)t * HEAD_DIM));
        const float2* vp = (const float2*)((t == pos) ? vnew : (vc + (size_t)t * HEAD_DIM));
        float2 k2 = kp[lane];
        float s[4];
        #pragma unroll
        for (int g = 0; g < 4; ++g) s[g] = q2[g].x * k2.x + q2[g].y * k2.y;
        #pragma unroll
        for (int off = 32; off; off >>= 1) {
            #pragma unroll
            for (int g = 0; g < 4; ++g) s[g] += __shfl_xor(s[g], off);
        }
        float2 v2 = vp[lane];
        #pragma unroll
        for (int g = 0; g < 4; ++g) {
            float sg = s[g] * SCALE;
            float mn = fmaxf(m[g], sg);
            float alpha = __expf(m[g] - mn);
            float pp    = __expf(sg - mn);
            l[g] = l[g] * alpha + pp;
            acc[g].x = acc[g].x * alpha + pp * v2.x;
            acc[g].y = acc[g].y * alpha + pp * v2.y;
            m[g] = mn;
        }
    }

    // cross-wave combine via LDS
    __shared__ float sm[4][4], sl[4][4];
    __shared__ float sacc[4][4][HEAD_DIM];
    #pragma unroll
    for (int g = 0; g < 4; ++g) {
        if (lane == 0) { sm[wave][g] = m[g]; sl[wave][g] = l[g]; }
        sacc[wave][g][2 * lane]     = acc[g].x;
        sacc[wave][g][2 * lane + 1] = acc[g].y;
    }
    __syncthreads();

    float* part = ws + PART + (size_t)blk * 4 * 130;
    if (tid < HEAD_DIM) {
        const int d = tid;
        #pragma unroll
        for (int g = 0; g < 4; ++g) {
            float M = fmaxf(fmaxf(sm[0][g], sm[1][g]), fmaxf(sm[2][g], sm[3][g]));
            float L = 0.f, A = 0.f;
            #pragma unroll
            for (int w = 0; w < 4; ++w) {
                float e = __expf(sm[w][g] - M);
                L += sl[w][g] * e;
                A += sacc[w][g][d] * e;
            }
            part[g * 130 + d] = A;
            if (d == 0) { part[g * 130 + 128] = M; part[g * 130 + 129] = L; }
        }
    }
}

// ---------------- Kernel 3: combine split partials -> attn_out -------------
__global__ __launch_bounds__(128) void comb_kernel(float* __restrict__ ws)
{
    const int blk = blockIdx.x;         // b*16 + h
    const int b = blk >> 4, h = blk & 15;
    const int kv = h >> 2, g = h & 3;
    const int d = threadIdx.x;
    const float* base = ws + PART + ((size_t)(b * NUM_KV + kv) * NSPLIT) * 4 * 130 + g * 130;

    float ms[NSPLIT], ls[NSPLIT];
    float M = -1e30f;
    #pragma unroll
    for (int s = 0; s < NSPLIT; ++s) {
        ms[s] = base[s * 520 + 128];
        ls[s] = base[s * 520 + 129];
        M = fmaxf(M, ms[s]);
    }
    float L = 0.f, A = 0.f;
    #pragma unroll
    for (int s = 0; s < NSPLIT; ++s) {
        float e = __expf(ms[s] - M);
        L += ls[s] * e;
        A += base[s * 520 + d] * e;
    }
    ws[AOUT + (size_t)b * HIDDEN + h * HEAD_DIM + d] = A / L;
}

// ---------------- Kernel 4: output projection ------------------------------
__global__ __launch_bounds__(256) void wo_kernel(
    const float* __restrict__ wo, const float* __restrict__ ws,
    float* __restrict__ out)
{
    __shared__ float xs[HIDDEN];
    const int blk = blockIdx.x;         // b*16 + chunk
    const int b = blk >> 4, chunk = blk & 15;
    const int tid = threadIdx.x, lane = tid & 63, wave = tid >> 6;

    const float4* xg = (const float4*)(ws + AOUT + (size_t)b * HIDDEN);
    for (int i = 0; i < HIDDEN / 4; i += 256)
        ((float4*)xs)[i + tid] = xg[i + tid];
    __syncthreads();

    const int r0 = chunk * 128;
    for (int r = wave; r < 128; r += 4) {
        const float4* wr = (const float4*)(wo + (size_t)(r0 + r) * HIDDEN);
        float sum = 0.f;
        #pragma unroll
        for (int j = 0; j < 8; ++j) {
            float4 w4 = wr[lane + 64 * j];
            float4 x4 = ((const float4*)xs)[lane + 64 * j];
            sum += w4.x * x4.x + w4.y * x4.y + w4.z * x4.z + w4.w * x4.w;
        }
        #pragma unroll
        for (int off = 32; off; off >>= 1) sum += __shfl_xor(sum, off);
        if (lane == 0) out[(size_t)b * HIDDEN + r0 + r] = sum;
    }
}

extern "C" void kernel_launch(void* const* d_in, const int* in_sizes, int n_in,
                              void* d_out, int out_size, void* d_ws, size_t ws_size,
                              hipStream_t stream) {
    const float* x        = (const float*)d_in[0];
    const float* position = (const float*)d_in[1];
    // d_in[2] mask: semantics replicated (t <= pos active), not read
    const float* kcache   = (const float*)d_in[3];
    const float* vcache   = (const float*)d_in[4];
    // d_in[5] onehot: position index already known from d_in[1]
    const float* wq       = (const float*)d_in[6];
    const float* wk       = (const float*)d_in[7];
    const float* wv       = (const float*)d_in[8];
    const float* wo       = (const float*)d_in[9];
    const float* qnw      = (const float*)d_in[10];
    const float* knw      = (const float*)d_in[11];
    float* ws  = (float*)d_ws;
    float* out = (float*)d_out;

    qkv_kernel<<<32 * 24, 256, 0, stream>>>(x, position, wq, wk, wv, qnw, knw, ws);
    attn_kernel<<<32 * NUM_KV * NSPLIT, 256, 0, stream>>>(kcache, vcache, position, ws);
    comb_kernel<<<32 * NUM_HEADS, 128, 0, stream>>>(ws);
    wo_kernel<<<32 * 16, 256, 0, stream>>>(wo, ws, out);
}